// Round 1
// baseline (322.634 us; speedup 1.0000x reference)
//
#include <hip/hip_runtime.h>
#include <hip/hip_bf16.h>

// Fused attention-like op, per (b,c) slice (256x256):
//   S = (Q K^T) * di ; A = softmax_rows(S) ; out[i,j] = sum_k A[j,k] V[i,k]
// B=8, C=64, H=W=256, fp32 in/out. MFMA bf16 with split-hi/lo for QK^T.

typedef __attribute__((ext_vector_type(8))) short bf16x8;
typedef __attribute__((ext_vector_type(4))) float f32x4;
typedef __attribute__((ext_vector_type(4))) short s16x4;

__device__ __forceinline__ unsigned short f2bf(float x) {
  return __builtin_bit_cast(unsigned short, __float2bfloat16(x));
}
__device__ __forceinline__ float bf2f(unsigned short u) {
  return __bfloat162float(__builtin_bit_cast(__hip_bfloat16, u));
}
__device__ __forceinline__ f32x4 mfma16(bf16x8 a, bf16x8 b, f32x4 c) {
  return __builtin_amdgcn_mfma_f32_16x16x32_bf16(a, b, c, 0, 0, 0);
}
// XOR swizzle for [32][256]-bf16 LDS tiles (512 B row stride): spreads the
// 16 rows a quarter-wave reads at one 16B column slot across 8 bank groups.
__device__ __forceinline__ int swzB(int row, int byteCol) {
  return row * 512 + (byteCol ^ ((row & 7) << 4));
}

__global__ __launch_bounds__(256) void attn_fused(
    const float* __restrict__ Q, const float* __restrict__ K,
    const float* __restrict__ V, const float* __restrict__ di,
    float* __restrict__ out) {
  __shared__ short KhiS[32 * 256];   // K-chunk hi; reused as V-chunk in mm2
  __shared__ short KloS[32 * 256];   // K-chunk lo; reused as attn (bf16) in mm2
  __shared__ float Sbuf[32 * 256];   // logits, fp32

  const int t = threadIdx.x;
  const int lane = t & 63;
  const int wv = t >> 6;          // 4 waves
  const int bc = blockIdx.x >> 3; // slice
  const int j0 = (blockIdx.x & 7) * 32;

  const float dival = di[0];
  const size_t base = (size_t)bc * 65536;
  const float* Qs = Q + base;
  const float* Ks = K + base;
  const float* Vs = V + base;
  float* Os = out + base;

  const int l15 = lane & 15;
  const int l4 = lane >> 4;
  const int sub0 = wv & 1;   // mm1: j-subtile  | mm2: i-subtile
  const int sub1 = wv >> 1;  // mm1: k-subtile  | mm2: j-subtile

  // ---- Q tile (32 rows) -> per-wave register fragments, hi+lo split ----
  bf16x8 qhi[8], qlo[8];
  {
    const float* qrow = Qs + (size_t)(j0 + sub0 * 16 + l15) * 256 + 8 * l4;
#pragma unroll
    for (int s = 0; s < 8; ++s) {
      const float* p = qrow + s * 32;
      f32x4 f0 = *(const f32x4*)p;
      f32x4 f1 = *(const f32x4*)(p + 4);
      bf16x8 h, l;
#pragma unroll
      for (int q = 0; q < 8; ++q) {
        float x = (q < 4) ? f0[q] : f1[q - 4];
        unsigned short hu = f2bf(x);
        h[q] = (short)hu;
        l[q] = (short)f2bf(x - bf2f(hu));
      }
      qhi[s] = h;
      qlo[s] = l;
    }
  }

  // fp32 32x256 chunk -> bf16 (hi[,lo]) into KhiS[,KloS], swizzled
  auto stage = [&](const float* src, bool withLo) {
    const int r = t >> 3, seg = t & 7;
#pragma unroll
    for (int e = 0; e < 4; ++e) {
      const int w0 = seg * 8 + e * 64;
      const float* p = src + r * 256 + w0;
      f32x4 f0 = *(const f32x4*)p;
      f32x4 f1 = *(const f32x4*)(p + 4);
      bf16x8 h, l;
#pragma unroll
      for (int q = 0; q < 8; ++q) {
        float x = (q < 4) ? f0[q] : f1[q - 4];
        unsigned short hu = f2bf(x);
        h[q] = (short)hu;
        l[q] = (short)f2bf(x - bf2f(hu));
      }
      const int off = swzB(r, w0 * 2);
      *(bf16x8*)((char*)KhiS + off) = h;
      if (withLo) *(bf16x8*)((char*)KloS + off) = l;
    }
  };

  // ---- matmul 1: S[j,k] = sum_w Q[j,w] K[k,w], split-bf16 (3 products) ----
  for (int ch = 0; ch < 8; ++ch) {
    __syncthreads();  // prior chunk's LDS reads complete
    stage(Ks + (size_t)ch * 32 * 256, true);
    __syncthreads();
    f32x4 acc = {0.f, 0.f, 0.f, 0.f};
    const int krow = sub1 * 16 + l15;
#pragma unroll
    for (int s = 0; s < 8; ++s) {
      const int off = swzB(krow, s * 64 + 16 * l4);
      bf16x8 bh = *(const bf16x8*)((const char*)KhiS + off);
      bf16x8 bl = *(const bf16x8*)((const char*)KloS + off);
      acc = mfma16(qhi[s], bh, acc);
      acc = mfma16(qlo[s], bh, acc);
      acc = mfma16(qhi[s], bl, acc);
    }
    const int jl = sub0 * 16 + l4 * 4;
    const int kcol = ch * 32 + sub1 * 16 + l15;
#pragma unroll
    for (int r = 0; r < 4; ++r) Sbuf[(jl + r) * 256 + kcol] = acc[r];
  }
  __syncthreads();  // S complete

  // ---- softmax rows (8 rows/wave, 64-lane parallel), A -> KloS as bf16 ----
  short* Ab = (short*)KloS;  // matmul1 done; Klo free
#pragma unroll
  for (int rr = 0; rr < 8; ++rr) {
    const int row = wv * 8 + rr;
    f32x4 v = *(const f32x4*)&Sbuf[row * 256 + lane * 4];
    float v0 = v[0] * dival, v1 = v[1] * dival, v2 = v[2] * dival,
          v3 = v[3] * dival;
    float m = fmaxf(fmaxf(v0, v1), fmaxf(v2, v3));
#pragma unroll
    for (int o = 32; o >= 1; o >>= 1) m = fmaxf(m, __shfl_xor(m, o));
    float e0 = __expf(v0 - m), e1 = __expf(v1 - m), e2 = __expf(v2 - m),
          e3 = __expf(v3 - m);
    float sum = e0 + e1 + e2 + e3;
#pragma unroll
    for (int o = 32; o >= 1; o >>= 1) sum += __shfl_xor(sum, o);
    const float inv = 1.0f / sum;
    s16x4 a;
    a[0] = (short)f2bf(e0 * inv);
    a[1] = (short)f2bf(e1 * inv);
    a[2] = (short)f2bf(e2 * inv);
    a[3] = (short)f2bf(e3 * inv);
    *(s16x4*)((char*)Ab + swzB(row, lane * 8)) = a;
  }

  // ---- matmul 2: out[i, j0+j] = sum_k A[j,k] V[i,k] ----
  for (int ci = 0; ci < 8; ++ci) {
    __syncthreads();  // A writes visible (first iter); prior V reads done
    stage(Vs + (size_t)ci * 32 * 256, false);  // V chunk -> KhiS (hi only)
    __syncthreads();
    f32x4 acc = {0.f, 0.f, 0.f, 0.f};
    const int vrow = sub0 * 16 + l15;  // i within chunk
    const int arow = sub1 * 16 + l15;  // j within tile
#pragma unroll
    for (int s = 0; s < 8; ++s) {
      const int offB = s * 64 + 16 * l4;
      bf16x8 va = *(const bf16x8*)((const char*)KhiS + swzB(vrow, offB));
      bf16x8 ab = *(const bf16x8*)((const char*)Ab + swzB(arow, offB));
      acc = mfma16(va, ab, acc);
    }
    const int ig0 = ci * 32 + sub0 * 16 + l4 * 4;
    const int jg = j0 + sub1 * 16 + l15;
#pragma unroll
    for (int r = 0; r < 4; ++r) Os[(size_t)(ig0 + r) * 256 + jg] = acc[r];
  }
}

extern "C" void kernel_launch(void* const* d_in, const int* in_sizes, int n_in,
                              void* d_out, int out_size, void* d_ws,
                              size_t ws_size, hipStream_t stream) {
  const float* Q = (const float*)d_in[0];
  const float* K = (const float*)d_in[1];
  const float* V = (const float*)d_in[2];
  const float* di = (const float*)d_in[3];
  float* out = (float*)d_out;
  const int BC = in_sizes[0] / (256 * 256);  // 512
  hipLaunchKernelGGL(attn_fused, dim3(BC * 8), dim3(256), 0, stream, Q, K, V,
                     di, out);
}

// Round 2
// 175.650 us; speedup vs baseline: 1.8368x; 1.8368x over previous
//
#include <hip/hip_runtime.h>
#include <hip/hip_bf16.h>

// Per (b,c) slice: S = (Q K^T)*di ; A = softmax_rows(S) ; out[i,j] = sum_k A[j,k] V[i,k]
// j-tile 128 per block (2 blocks/slice), 8 waves, S in registers, A in LDS.

typedef __attribute__((ext_vector_type(8))) short bf16x8;
typedef __attribute__((ext_vector_type(4))) float f32x4;

__device__ __forceinline__ unsigned short f2bf(float x) {
  return __builtin_bit_cast(unsigned short, __float2bfloat16(x));
}
__device__ __forceinline__ float bf2f(unsigned short u) {
  return __bfloat162float(__builtin_bit_cast(__hip_bfloat16, u));
}
__device__ __forceinline__ f32x4 mfma16(bf16x8 a, bf16x8 b, f32x4 c) {
  return __builtin_amdgcn_mfma_f32_16x16x32_bf16(a, b, c, 0, 0, 0);
}
// swizzled byte offset in a [rows][256]-bf16 tile (512 B row stride)
__device__ __forceinline__ int swzB(int row, int byteCol) {
  return row * 512 + (byteCol ^ ((row & 7) << 4));
}

__global__ __launch_bounds__(512, 2) void attn_fused2(
    const float* __restrict__ Q, const float* __restrict__ K,
    const float* __restrict__ V, const float* __restrict__ di,
    float* __restrict__ out) {
  __shared__ short Shi[2][32 * 256];  // K hi (mm1) / V (mm2), double-buffered
  __shared__ short Slo[2][32 * 256];  // K lo (mm1)
  __shared__ short Abuf[128 * 256];   // attn weights bf16, swizzled

  const int t = threadIdx.x;
  const int lane = t & 63;
  const int wv = t >> 6;   // 0..7
  const int l15 = lane & 15;
  const int l4 = lane >> 4;  // 0..3
  const int bc = blockIdx.x >> 1;
  const int j0 = (blockIdx.x & 1) << 7;  // 0 or 128

  const float dival = di[0];
  const size_t base = (size_t)bc << 16;
  const float* Qs = Q + base;
  const float* Ks = K + base;
  const float* Vs = V + base;
  float* Os = out + base;

  // staging coords: thread loads 16 consecutive floats of a 32x256 chunk
  const int sr = t >> 4;         // row 0..31
  const int sc = (t & 15) << 4;  // float col, step 16

  f32x4 c0, c1, c2, c3;  // prefetch registers (fp32 chunk data)

  // ---- prologue: K chunk 0 loads in flight; Q fragments -> registers ----
  {
    const float* p = Ks + sr * 256 + sc;
    c0 = *(const f32x4*)p;
    c1 = *(const f32x4*)(p + 4);
    c2 = *(const f32x4*)(p + 8);
    c3 = *(const f32x4*)(p + 12);
  }
  bf16x8 qh[8], ql[8];  // wave's 16 Q rows, hi/lo split (A-operand layout)
  {
    const float* qrow = Qs + (size_t)(j0 + wv * 16 + l15) * 256 + 8 * l4;
#pragma unroll
    for (int s = 0; s < 8; ++s) {
      f32x4 f0 = *(const f32x4*)(qrow + 32 * s);
      f32x4 f1 = *(const f32x4*)(qrow + 32 * s + 4);
      bf16x8 h, l;
#pragma unroll
      for (int q = 0; q < 8; ++q) {
        float x = (q < 4) ? f0[q] : f1[q - 4];
        unsigned short hu = f2bf(x);
        h[q] = (short)hu;
        l[q] = (short)f2bf(x - bf2f(hu));
      }
      qh[s] = h;
      ql[s] = l;
    }
  }

  f32x4 acc[16];  // S[16 rows][256 cols] fragments, rows j = wv*16+4*l4+r
#pragma unroll
  for (int i = 0; i < 16; ++i) acc[i] = (f32x4){0.f, 0.f, 0.f, 0.f};

  // ---- matmul 1: S = Q K^T (split bf16, 3 MFMA products) ----
#pragma unroll
  for (int ch = 0; ch < 8; ++ch) {
    short* hi = Shi[ch & 1];
    short* lo = Slo[ch & 1];
    {  // convert prefetched fp32 -> hi/lo bf16, write LDS (swizzled)
      float f[16];
      *(f32x4*)(f + 0) = c0;
      *(f32x4*)(f + 4) = c1;
      *(f32x4*)(f + 8) = c2;
      *(f32x4*)(f + 12) = c3;
      bf16x8 h0, h1, L0, L1;
#pragma unroll
      for (int q = 0; q < 8; ++q) {
        unsigned short hu = f2bf(f[q]);
        h0[q] = (short)hu;
        L0[q] = (short)f2bf(f[q] - bf2f(hu));
        unsigned short hv = f2bf(f[q + 8]);
        h1[q] = (short)hv;
        L1[q] = (short)f2bf(f[q + 8] - bf2f(hv));
      }
      const int b0 = swzB(sr, sc * 2);
      const int b1 = swzB(sr, sc * 2 + 16);
      *(bf16x8*)((char*)hi + b0) = h0;
      *(bf16x8*)((char*)hi + b1) = h1;
      *(bf16x8*)((char*)lo + b0) = L0;
      *(bf16x8*)((char*)lo + b1) = L1;
    }
    __syncthreads();
    if (ch < 7) {  // prefetch next chunk AFTER barrier: flies under MFMA
      const float* p = Ks + (ch + 1) * 32 * 256 + sr * 256 + sc;
      c0 = *(const f32x4*)p;
      c1 = *(const f32x4*)(p + 4);
      c2 = *(const f32x4*)(p + 8);
      c3 = *(const f32x4*)(p + 12);
    }
#pragma unroll
    for (int kf = 0; kf < 2; ++kf) {
      f32x4 a = acc[2 * ch + kf];
      const int kr = kf * 16 + l15;
#pragma unroll
      for (int s = 0; s < 8; ++s) {
        const int off = swzB(kr, 64 * s + 16 * l4);
        bf16x8 bh = *(const bf16x8*)((const char*)hi + off);
        bf16x8 bl = *(const bf16x8*)((const char*)lo + off);
        a = mfma16(qh[s], bh, a);
        a = mfma16(ql[s], bh, a);
        a = mfma16(qh[s], bl, a);
      }
      acc[2 * ch + kf] = a;
    }
  }

  // ---- prefetch V chunk 0 (flies under softmax) ----
  {
    const float* p = Vs + sr * 256 + sc;
    c0 = *(const f32x4*)p;
    c1 = *(const f32x4*)(p + 4);
    c2 = *(const f32x4*)(p + 8);
    c3 = *(const f32x4*)(p + 12);
  }

  // ---- softmax, fully in-register ----
  // lane holds S[j = wv*16 + 4*l4 + r][k = kfi*16 + l15]
  float mx[4] = {-1e30f, -1e30f, -1e30f, -1e30f};
#pragma unroll
  for (int kfi = 0; kfi < 16; ++kfi)
#pragma unroll
    for (int r = 0; r < 4; ++r) {
      acc[kfi][r] *= dival;
      mx[r] = fmaxf(mx[r], acc[kfi][r]);
    }
#pragma unroll
  for (int o = 1; o <= 8; o <<= 1)
#pragma unroll
    for (int r = 0; r < 4; ++r) mx[r] = fmaxf(mx[r], __shfl_xor(mx[r], o));
  float sm[4] = {0.f, 0.f, 0.f, 0.f};
#pragma unroll
  for (int kfi = 0; kfi < 16; ++kfi)
#pragma unroll
    for (int r = 0; r < 4; ++r) {
      acc[kfi][r] = __expf(acc[kfi][r] - mx[r]);
      sm[r] += acc[kfi][r];
    }
#pragma unroll
  for (int o = 1; o <= 8; o <<= 1)
#pragma unroll
    for (int r = 0; r < 4; ++r) sm[r] += __shfl_xor(sm[r], o);
#pragma unroll
  for (int r = 0; r < 4; ++r) sm[r] = 1.0f / sm[r];
  // write A (bf16) into swizzled LDS: row j, col k
#pragma unroll
  for (int kfi = 0; kfi < 16; ++kfi)
#pragma unroll
    for (int r = 0; r < 4; ++r) {
      const int j = wv * 16 + 4 * l4 + r;
      const int byteoff = swzB(j, 2 * (kfi * 16 + l15));
      *(short*)((char*)Abuf + byteoff) = (short)f2bf(acc[kfi][r] * sm[r]);
    }
  __syncthreads();  // A visible to all waves

  // ---- matmul 2: out[i, j0+j] = sum_k A[j,k] V[i,k] ----
  const int isub = wv >> 2;  // 0..1
  const int jsub = wv & 3;   // 0..3
#pragma unroll
  for (int ci = 0; ci < 8; ++ci) {
    short* vb = Shi[ci & 1];
    {  // convert prefetched V fp32 -> bf16 (hi only), write LDS
      float f[16];
      *(f32x4*)(f + 0) = c0;
      *(f32x4*)(f + 4) = c1;
      *(f32x4*)(f + 8) = c2;
      *(f32x4*)(f + 12) = c3;
      bf16x8 h0, h1;
#pragma unroll
      for (int q = 0; q < 8; ++q) {
        h0[q] = (short)f2bf(f[q]);
        h1[q] = (short)f2bf(f[q + 8]);
      }
      *(bf16x8*)((char*)vb + swzB(sr, sc * 2)) = h0;
      *(bf16x8*)((char*)vb + swzB(sr, sc * 2 + 16)) = h1;
    }
    __syncthreads();
    if (ci < 7) {  // prefetch next V chunk after barrier
      const float* p = Vs + (ci + 1) * 32 * 256 + sr * 256 + sc;
      c0 = *(const f32x4*)p;
      c1 = *(const f32x4*)(p + 4);
      c2 = *(const f32x4*)(p + 8);
      c3 = *(const f32x4*)(p + 12);
    }
    f32x4 a0 = {0.f, 0.f, 0.f, 0.f}, a1 = {0.f, 0.f, 0.f, 0.f};
    const int vr = isub * 16 + l15;
#pragma unroll
    for (int s = 0; s < 8; ++s) {
      const int offs = 64 * s + 16 * l4;
      bf16x8 va = *(const bf16x8*)((const char*)vb + swzB(vr, offs));
      bf16x8 ab0 =
          *(const bf16x8*)((const char*)Abuf + swzB(jsub * 32 + l15, offs));
      bf16x8 ab1 = *(const bf16x8*)((const char*)Abuf +
                                    swzB(jsub * 32 + 16 + l15, offs));
      a0 = mfma16(va, ab0, a0);
      a1 = mfma16(va, ab1, a1);
    }
    const int ig = ci * 32 + isub * 16 + 4 * l4;
    const int jg = j0 + jsub * 32 + l15;
#pragma unroll
    for (int r = 0; r < 4; ++r) {
      Os[(size_t)(ig + r) * 256 + jg] = a0[r];
      Os[(size_t)(ig + r) * 256 + jg + 16] = a1[r];
    }
  }
}

extern "C" void kernel_launch(void* const* d_in, const int* in_sizes, int n_in,
                              void* d_out, int out_size, void* d_ws,
                              size_t ws_size, hipStream_t stream) {
  const float* Q = (const float*)d_in[0];
  const float* K = (const float*)d_in[1];
  const float* V = (const float*)d_in[2];
  const float* di = (const float*)d_in[3];
  float* out = (float*)d_out;
  const int BC = in_sizes[0] / (256 * 256);  // 512 slices
  hipLaunchKernelGGL(attn_fused2, dim3(BC * 2), dim3(512), 0, stream, Q, K, V,
                     di, out);
}

// Round 3
// 167.337 us; speedup vs baseline: 1.9280x; 1.0497x over previous
//
#include <hip/hip_runtime.h>
#include <hip/hip_bf16.h>

// Per (b,c) slice: S = (Q K^T)*di ; A = softmax_rows(S) ; out[i,j] = sum_k A[j,k] V[i,k]
// j-tile 128 (2 blocks/slice, XCD-paired), 8 waves.
// mm1: 16x16x32 split-bf16 (3 products), S in regs, in-register softmax.
// mm2: 32x32x16, wave tile 64i x 64j, V staged as [256 i][64 k] bf16 chunks.

typedef __attribute__((ext_vector_type(8))) short bf16x8;
typedef __attribute__((ext_vector_type(4))) float f32x4;
typedef __attribute__((ext_vector_type(16))) float f32x16;

__device__ __forceinline__ unsigned short f2bf(float x) {
  return __builtin_bit_cast(unsigned short, __float2bfloat16(x));
}
__device__ __forceinline__ float bf2f(unsigned short u) {
  return __bfloat162float(__builtin_bit_cast(__hip_bfloat16, u));
}
__device__ __forceinline__ f32x4 mfma16(bf16x8 a, bf16x8 b, f32x4 c) {
  return __builtin_amdgcn_mfma_f32_16x16x32_bf16(a, b, c, 0, 0, 0);
}
__device__ __forceinline__ f32x16 mfma32(bf16x8 a, bf16x8 b, f32x16 c) {
  return __builtin_amdgcn_mfma_f32_32x32x16_bf16(a, b, c, 0, 0, 0);
}
// 512B-row-stride tiles ([*][256] bf16): XOR all 4 row bits into 16B-slot idx
__device__ __forceinline__ int swzA(int row, int byteCol) {
  return row * 512 + (byteCol ^ ((row & 15) << 4));
}
// 128B-row-stride tile ([256][64] bf16): 3 slot bits available
__device__ __forceinline__ int swzV(int row, int byteCol) {
  return row * 128 + (byteCol ^ ((row & 7) << 4));
}

__global__ __launch_bounds__(512) void attn_fused3(
    const float* __restrict__ Q, const float* __restrict__ K,
    const float* __restrict__ V, const float* __restrict__ di,
    float* __restrict__ out) {
  __shared__ short KhiS[2][32 * 256];  // 32KB; aliased as Vlds in mm2
  __shared__ short KloS[2][32 * 256];  // 32KB
  __shared__ short Abuf[128 * 256];    // 64KB attn bf16, swizzled
  short* Vlds = (short*)KhiS;          // [256][64] bf16 = 32KB (alias)

  const int t = threadIdx.x;
  const int lane = t & 63;
  const int wv = t >> 6;
  const int l15 = lane & 15;
  const int l4 = lane >> 4;   // 0..3
  const int l31 = lane & 31;
  const int h5 = lane >> 5;   // 0..1

  // XCD-pair swizzle: both halves of a slice get the same bid%8 -> same XCD L2
  const int bid = blockIdx.x;
  const int bc = (bid >> 4) * 8 + (bid & 7);
  const int j0 = ((bid >> 3) & 1) << 7;

  const float dival = di[0];
  const size_t base = (size_t)bc << 16;
  const float* Qs = Q + base;
  const float* Ks = K + base;
  const float* Vs = V + base;
  float* Os = out + base;

  // K staging coords: thread loads 16 consecutive floats of a 32x256 chunk
  const int sr = t >> 4;
  const int sc = (t & 15) << 4;

  f32x4 c0, c1, c2, c3;
  {  // K chunk 0 loads in flight
    const float* p = Ks + sr * 256 + sc;
    c0 = *(const f32x4*)p;
    c1 = *(const f32x4*)(p + 4);
    c2 = *(const f32x4*)(p + 8);
    c3 = *(const f32x4*)(p + 12);
  }
  bf16x8 qh[8], ql[8];  // wave's 16 Q rows, hi/lo split
  {
    const float* qrow = Qs + (size_t)(j0 + wv * 16 + l15) * 256 + 8 * l4;
#pragma unroll
    for (int s = 0; s < 8; ++s) {
      f32x4 f0 = *(const f32x4*)(qrow + 32 * s);
      f32x4 f1 = *(const f32x4*)(qrow + 32 * s + 4);
      bf16x8 hh, ll;
#pragma unroll
      for (int q = 0; q < 8; ++q) {
        float x = (q < 4) ? f0[q] : f1[q - 4];
        unsigned short hu = f2bf(x);
        hh[q] = (short)hu;
        ll[q] = (short)f2bf(x - bf2f(hu));
      }
      qh[s] = hh;
      ql[s] = ll;
    }
  }

  f32x4 acc[16];  // S rows j = wv*16 + 4*l4 + r ; cols k = 16*kfi + l15
#pragma unroll
  for (int i = 0; i < 16; ++i) acc[i] = (f32x4){0.f, 0.f, 0.f, 0.f};

  // ---- matmul 1 ----
#pragma unroll
  for (int ch = 0; ch < 8; ++ch) {
    short* hi = KhiS[ch & 1];
    short* lo = KloS[ch & 1];
    {
      float f[16];
      *(f32x4*)(f + 0) = c0;
      *(f32x4*)(f + 4) = c1;
      *(f32x4*)(f + 8) = c2;
      *(f32x4*)(f + 12) = c3;
      bf16x8 h0, h1, L0, L1;
#pragma unroll
      for (int q = 0; q < 8; ++q) {
        unsigned short hu = f2bf(f[q]);
        h0[q] = (short)hu;
        L0[q] = (short)f2bf(f[q] - bf2f(hu));
        unsigned short hv = f2bf(f[q + 8]);
        h1[q] = (short)hv;
        L1[q] = (short)f2bf(f[q + 8] - bf2f(hv));
      }
      const int b0 = swzA(sr, sc * 2);
      const int b1 = swzA(sr, sc * 2 + 16);
      *(bf16x8*)((char*)hi + b0) = h0;
      *(bf16x8*)((char*)hi + b1) = h1;
      *(bf16x8*)((char*)lo + b0) = L0;
      *(bf16x8*)((char*)lo + b1) = L1;
    }
    __syncthreads();
    if (ch < 7) {  // prefetch next K chunk; flies under MFMA
      const float* p = Ks + (ch + 1) * 32 * 256 + sr * 256 + sc;
      c0 = *(const f32x4*)p;
      c1 = *(const f32x4*)(p + 4);
      c2 = *(const f32x4*)(p + 8);
      c3 = *(const f32x4*)(p + 12);
    }
#pragma unroll
    for (int kf = 0; kf < 2; ++kf) {
      f32x4 a = acc[2 * ch + kf];
      const int kr = kf * 16 + l15;
#pragma unroll
      for (int s = 0; s < 8; ++s) {
        const int off = swzA(kr, 64 * s + 16 * l4);
        bf16x8 bh = *(const bf16x8*)((const char*)hi + off);
        bf16x8 bl = *(const bf16x8*)((const char*)lo + off);
        a = mfma16(qh[s], bh, a);
        a = mfma16(ql[s], bh, a);
        a = mfma16(qh[s], bl, a);
      }
      acc[2 * ch + kf] = a;
    }
  }

  // ---- V k-chunk 0 prefetch (flies under softmax): [256 i][64 k] cols 0..63
  const int vr = t >> 1;              // i-row 0..255
  const int vh = (t & 1) * 32;        // float col offset within chunk
  f32x4 vc0, vc1, vc2, vc3, vc4, vc5, vc6, vc7;
  {
    const float* p = Vs + (size_t)vr * 256 + vh;
    vc0 = *(const f32x4*)p;
    vc1 = *(const f32x4*)(p + 4);
    vc2 = *(const f32x4*)(p + 8);
    vc3 = *(const f32x4*)(p + 12);
    vc4 = *(const f32x4*)(p + 16);
    vc5 = *(const f32x4*)(p + 20);
    vc6 = *(const f32x4*)(p + 24);
    vc7 = *(const f32x4*)(p + 28);
  }

  // ---- softmax (in-register) ----
  float mx[4] = {-1e30f, -1e30f, -1e30f, -1e30f};
#pragma unroll
  for (int kfi = 0; kfi < 16; ++kfi)
#pragma unroll
    for (int r = 0; r < 4; ++r) {
      acc[kfi][r] *= dival;
      mx[r] = fmaxf(mx[r], acc[kfi][r]);
    }
#pragma unroll
  for (int o = 1; o <= 8; o <<= 1)
#pragma unroll
    for (int r = 0; r < 4; ++r) mx[r] = fmaxf(mx[r], __shfl_xor(mx[r], o));
  float sm[4] = {0.f, 0.f, 0.f, 0.f};
#pragma unroll
  for (int kfi = 0; kfi < 16; ++kfi)
#pragma unroll
    for (int r = 0; r < 4; ++r) {
      acc[kfi][r] = __expf(acc[kfi][r] - mx[r]);
      sm[r] += acc[kfi][r];
    }
#pragma unroll
  for (int o = 1; o <= 8; o <<= 1)
#pragma unroll
    for (int r = 0; r < 4; ++r) sm[r] += __shfl_xor(sm[r], o);
#pragma unroll
  for (int r = 0; r < 4; ++r) sm[r] = 1.0f / sm[r];
#pragma unroll
  for (int kfi = 0; kfi < 16; ++kfi)
#pragma unroll
    for (int r = 0; r < 4; ++r) {
      const int j = wv * 16 + 4 * l4 + r;
      *(short*)((char*)Abuf + swzA(j, 2 * (kfi * 16 + l15))) =
          (short)f2bf(acc[kfi][r] * sm[r]);
    }
  __syncthreads();  // A visible; all mm1 K-LDS reads done (Vlds alias safe)

  // ---- matmul 2: 32x32x16, wave tile 64i x 64j ----
  const int ig0 = (wv >> 1) * 64;
  const int jg0 = (wv & 1) * 64;
  f32x16 a00 = {}, a01 = {}, a10 = {}, a11 = {};

#pragma unroll
  for (int kc = 0; kc < 4; ++kc) {
    {  // convert prefetched V fp32 -> bf16, write Vlds[vr][vh..vh+31]
      float f[32];
      *(f32x4*)(f + 0) = vc0;
      *(f32x4*)(f + 4) = vc1;
      *(f32x4*)(f + 8) = vc2;
      *(f32x4*)(f + 12) = vc3;
      *(f32x4*)(f + 16) = vc4;
      *(f32x4*)(f + 20) = vc5;
      *(f32x4*)(f + 24) = vc6;
      *(f32x4*)(f + 28) = vc7;
#pragma unroll
      for (int s = 0; s < 4; ++s) {
        bf16x8 hh;
#pragma unroll
        for (int q = 0; q < 8; ++q) hh[q] = (short)f2bf(f[s * 8 + q]);
        *(bf16x8*)((char*)Vlds + swzV(vr, (vh + s * 8) * 2)) = hh;
      }
    }
    __syncthreads();  // V chunk visible
    if (kc < 3) {     // prefetch next V k-chunk; flies under MFMA
      const float* p = Vs + (size_t)vr * 256 + (kc + 1) * 64 + vh;
      vc0 = *(const f32x4*)p;
      vc1 = *(const f32x4*)(p + 4);
      vc2 = *(const f32x4*)(p + 8);
      vc3 = *(const f32x4*)(p + 12);
      vc4 = *(const f32x4*)(p + 16);
      vc5 = *(const f32x4*)(p + 20);
      vc6 = *(const f32x4*)(p + 24);
      vc7 = *(const f32x4*)(p + 28);
    }
#pragma unroll
    for (int ks = 0; ks < 4; ++ks) {
      const int colV = 32 * ks + 16 * h5;
      bf16x8 va0 = *(const bf16x8*)((const char*)Vlds + swzV(ig0 + l31, colV));
      bf16x8 va1 =
          *(const bf16x8*)((const char*)Vlds + swzV(ig0 + 32 + l31, colV));
      const int colA = 2 * (kc * 64 + ks * 16) + 16 * h5;
      bf16x8 ab0 = *(const bf16x8*)((const char*)Abuf + swzA(jg0 + l31, colA));
      bf16x8 ab1 =
          *(const bf16x8*)((const char*)Abuf + swzA(jg0 + 32 + l31, colA));
      a00 = mfma32(va0, ab0, a00);
      a01 = mfma32(va0, ab1, a01);
      a10 = mfma32(va1, ab0, a10);
      a11 = mfma32(va1, ab1, a11);
    }
    __syncthreads();  // all reads done before next chunk overwrite
  }

  // ---- stores: D 32x32 layout col=l31, row=(reg&3)+8*(reg>>2)+4*h5 ----
#pragma unroll
  for (int reg = 0; reg < 16; ++reg) {
    const int rw = (reg & 3) + 8 * (reg >> 2) + 4 * h5;
    const int col = j0 + jg0 + l31;
    Os[(size_t)(ig0 + rw) * 256 + col] = a00[reg];
    Os[(size_t)(ig0 + rw) * 256 + col + 32] = a01[reg];
    Os[(size_t)(ig0 + 32 + rw) * 256 + col] = a10[reg];
    Os[(size_t)(ig0 + 32 + rw) * 256 + col + 32] = a11[reg];
  }
}

extern "C" void kernel_launch(void* const* d_in, const int* in_sizes, int n_in,
                              void* d_out, int out_size, void* d_ws,
                              size_t ws_size, hipStream_t stream) {
  const float* Q = (const float*)d_in[0];
  const float* K = (const float*)d_in[1];
  const float* V = (const float*)d_in[2];
  const float* di = (const float*)d_in[3];
  float* out = (float*)d_out;
  const int BC = in_sizes[0] / (256 * 256);  // 512 slices
  hipLaunchKernelGGL(attn_fused3, dim3(BC * 2), dim3(512), 0, stream, Q, K, V,
                     di, out);
}